// Round 1
// baseline (142.759 us; speedup 1.0000x reference)
//
#include <hip/hip_runtime.h>

#define BB 4
#define TT 1024
#define DD 128
#define LL 16
#define CC 64   // TT/LL
#define EPSV 1e-6f

// workspace offsets (floats)
#define OFF_QC   0
#define OFF_KH   (OFF_QC + BB*TT*DD)
#define OFF_V    (OFF_KH + BB*TT*DD)
#define OFF_CL   (OFF_V  + BB*TT*DD)
#define OFF_KS   (OFF_CL + BB*CC*DD)
#define OFF_Z0   (OFF_KS + BB*CC*DD)
#define OFF_U    (OFF_Z0 + BB*CC*DD)
#define OFF_S0   (OFF_U  + BB*CC*DD*DD)
// total = 3*BTD + 3*BCD + 2*BCDD = 1572864 + 98304 + 8388608 floats ~= 40.2 MB

// ---------------------------------------------------------------------------
// Kernel 1: per (b,chunk) block. Computes q,k,v,a projections for the 16 rows
// of the chunk, applies activations, does the in-chunk gate cumprod c_t[i],
// writes qc = relu(q)*c, kh = relu(k)/c, v, cL, Ksum, and U = kb^T V where
// kb = relu(k)*cL/c.
// ---------------------------------------------------------------------------
__global__ __launch_bounds__(256) void k_proj(
    const float* __restrict__ x,
    const float* __restrict__ Wq, const float* __restrict__ bq,
    const float* __restrict__ Wk, const float* __restrict__ bk,
    const float* __restrict__ Wv, const float* __restrict__ bv,
    const float* __restrict__ Wa, const float* __restrict__ ba,
    float* __restrict__ ws)
{
    __shared__ float xs[LL][DD];
    __shared__ float cs[LL][DD];
    __shared__ float kbs[LL][DD];
    __shared__ float vsm[LL][DD];

    const int tid = threadIdx.x;
    const int bc  = blockIdx.x;        // b*CC + ch
    const int b   = bc / CC;
    const int ch  = bc % CC;
    const int t0  = ch * LL;

    // ---- load x tile [16][128] ----
    const float4* xg = (const float4*)(x + (size_t)(b*TT + t0)*DD);
    float4* xsv = (float4*)&xs[0][0];
    xsv[tid]       = xg[tid];
    xsv[tid + 256] = xg[tid + 256];
    __syncthreads();

    // ---- GEMM: wave m handles matrix m; thread owns 2 output columns ----
    const int m  = tid >> 6;           // 0:q 1:k 2:v 3:a  (wave-uniform)
    const int j2 = tid & 63;
    const int j0 = j2*2, j1 = j0+1;
    const float* W; const float* bias;
    if      (m==0){W=Wq;bias=bq;}
    else if (m==1){W=Wk;bias=bk;}
    else if (m==2){W=Wv;bias=bv;}
    else          {W=Wa;bias=ba;}

    float acc0[LL], acc1[LL];
    {
        float b0 = bias[j0], b1 = bias[j1];
        #pragma unroll
        for (int t=0;t<LL;t++){acc0[t]=b0;acc1[t]=b1;}
    }
    const float* w0p = W + j0*DD;
    const float* w1p = W + j1*DD;
    #pragma unroll 4
    for (int kk=0; kk<DD; kk+=4){
        float4 w0 = *(const float4*)(w0p+kk);
        float4 w1 = *(const float4*)(w1p+kk);
        #pragma unroll
        for (int t=0;t<LL;t++){
            float4 xv = *(const float4*)(&xs[t][kk]);
            acc0[t] = fmaf(w0.x,xv.x, fmaf(w0.y,xv.y, fmaf(w0.z,xv.z, fmaf(w0.w,xv.w, acc0[t]))));
            acc1[t] = fmaf(w1.x,xv.x, fmaf(w1.y,xv.y, fmaf(w1.z,xv.z, fmaf(w1.w,xv.w, acc1[t]))));
        }
    }

    // ---- a-wave: sigmoid + cumprod -> cs, cL ----
    if (m==3){
        float c0=1.f, c1=1.f;
        #pragma unroll
        for (int t=0;t<LL;t++){
            float g0 = 1.f/(1.f+__expf(-acc0[t]));
            float g1 = 1.f/(1.f+__expf(-acc1[t]));
            c0*=g0; c1*=g1;
            cs[t][j0]=c0; cs[t][j1]=c1;
        }
        float* cLg = ws + OFF_CL + (size_t)bc*DD;
        cLg[j0]=c0; cLg[j1]=c1;
    }
    __syncthreads();

    if (m==0){ // qc = relu(q)*c
        float* qcg = ws + OFF_QC + (size_t)(b*TT + t0)*DD;
        #pragma unroll
        for (int t=0;t<LL;t++){
            float q0 = fmaxf(acc0[t],0.f)*cs[t][j0];
            float q1 = fmaxf(acc1[t],0.f)*cs[t][j1];
            *(float2*)(qcg + t*DD + j0) = make_float2(q0,q1);
        }
    } else if (m==1){ // kh = relu(k)/c ; kb = kh*cL ; Ksum
        float cL0 = cs[LL-1][j0], cL1 = cs[LL-1][j1];
        float ks0=0.f, ks1=0.f;
        float* khg = ws + OFF_KH + (size_t)(b*TT + t0)*DD;
        #pragma unroll
        for (int t=0;t<LL;t++){
            float k0 = fmaxf(acc0[t],0.f);
            float k1 = fmaxf(acc1[t],0.f);
            float kh0 = k0/cs[t][j0];
            float kh1 = k1/cs[t][j1];
            *(float2*)(khg + t*DD + j0) = make_float2(kh0,kh1);
            float kb0 = kh0*cL0, kb1 = kh1*cL1;
            kbs[t][j0]=kb0; kbs[t][j1]=kb1;
            ks0+=kb0; ks1+=kb1;
        }
        float* ksg = ws + OFF_KS + (size_t)bc*DD;
        ksg[j0]=ks0; ksg[j1]=ks1;
    } else if (m==2){ // v
        float* vg = ws + OFF_V + (size_t)(b*TT + t0)*DD;
        #pragma unroll
        for (int t=0;t<LL;t++){
            vsm[t][j0]=acc0[t]; vsm[t][j1]=acc1[t];
            *(float2*)(vg + t*DD + j0) = make_float2(acc0[t],acc1[t]);
        }
    }
    __syncthreads();

    // ---- U[i][j] = sum_u kb[u][i]*v[u][j] ; thread: j = tid&127, ih = tid>>7 ----
    const int j  = tid & 127;
    const int ih = tid >> 7;
    float vr[LL];
    #pragma unroll
    for (int u=0;u<LL;u++) vr[u]=vsm[u][j];
    float* Ug = ws + OFF_U + (size_t)bc*DD*DD;
    #pragma unroll 2
    for (int i4=0;i4<16;i4++){
        int i = ih*64 + i4*4;
        float a0=0.f,a1=0.f,a2=0.f,a3=0.f;
        #pragma unroll
        for (int u=0;u<LL;u++){
            float4 kb4 = *(const float4*)(&kbs[u][i]);
            float vu = vr[u];
            a0 = fmaf(kb4.x,vu,a0); a1 = fmaf(kb4.y,vu,a1);
            a2 = fmaf(kb4.z,vu,a2); a3 = fmaf(kb4.w,vu,a3);
        }
        Ug[(size_t)(i+0)*DD + j]=a0; Ug[(size_t)(i+1)*DD + j]=a1;
        Ug[(size_t)(i+2)*DD + j]=a2; Ug[(size_t)(i+3)*DD + j]=a3;
    }
}

// ---------------------------------------------------------------------------
// Kernel 2: per-element scan over chunks. Thread (b,i,j):
//   s0[b,c] = s ; s = cL[b,c,i]*s + U[b,c,i,j]
// z chain done redundantly per block (lane 0 stores).
// Fully parallel across 65536 (b,i,j) triples — no synchronization.
// ---------------------------------------------------------------------------
__global__ __launch_bounds__(128) void k_scan(float* __restrict__ ws)
{
    const int bi = blockIdx.x;      // b*DD + i
    const int b  = bi >> 7;
    const int i  = bi & 127;
    const int j  = threadIdx.x;

    const float* U   = ws + OFF_U;
    float*       s0  = ws + OFF_S0;
    const float* cLg = ws + OFF_CL;
    const float* Ksg = ws + OFF_KS;
    float*       z0g = ws + OFF_Z0;

    const size_t base  = (size_t)b*CC*DD*DD + (size_t)i*DD + j;
    const int    cbase = b*CC*DD + i;

    float s = 0.f, z = 0.f;
    #pragma unroll 4
    for (int ch=0; ch<CC; ch++){
        s0[base + (size_t)ch*DD*DD] = s;
        if (j==0) z0g[cbase + ch*DD] = z;
        float cl = cLg[cbase + ch*DD];
        float u  = U  [base + (size_t)ch*DD*DD];
        float ks = Ksg[cbase + ch*DD];
        s = fmaf(cl, s, u);
        z = fmaf(cl, z, ks);
    }
}

// ---------------------------------------------------------------------------
// Kernel 3: per (b,chunk) block: scores S[t][u] = qc_t . kh_u (masked u<=t),
// den_t = eps + qc_t.z0 + rowsum(S), y = (qc @ s0 + S @ V) / den.
// ---------------------------------------------------------------------------
__global__ __launch_bounds__(256) void k_out(const float* __restrict__ ws, float* __restrict__ y)
{
    __shared__ float qcs[LL][DD+4];
    __shared__ float khs[LL][DD+4];
    __shared__ float vsm[LL][DD+4];
    __shared__ float Ss[LL][LL];
    __shared__ float denS[LL];
    __shared__ float z0s[DD];
    __shared__ float s0s[16][DD+4];

    const int tid = threadIdx.x;
    const int bc  = blockIdx.x;
    const int b   = bc / CC;
    const int ch  = bc % CC;
    const int t0  = ch * LL;

    // coop load qc/kh/v chunk tiles (2048 floats each)
    {
        const float4* qcg = (const float4*)(ws + OFF_QC + (size_t)(b*TT+t0)*DD);
        const float4* khg = (const float4*)(ws + OFF_KH + (size_t)(b*TT+t0)*DD);
        const float4* vg  = (const float4*)(ws + OFF_V  + (size_t)(b*TT+t0)*DD);
        #pragma unroll
        for (int rep=0; rep<2; rep++){
            int f = tid + rep*256;
            int t = f >> 5, k4 = f & 31;
            *(float4*)&qcs[t][k4*4] = qcg[f];
            *(float4*)&khs[t][k4*4] = khg[f];
            *(float4*)&vsm[t][k4*4] = vg [f];
        }
        if (tid < DD) z0s[tid] = ws[OFF_Z0 + (size_t)bc*DD + tid];
    }
    __syncthreads();

    // scores
    {
        int t = tid >> 4, u = tid & 15;
        float s = 0.f;
        #pragma unroll 8
        for (int k4=0; k4<32; k4++){
            float4 q4 = *(const float4*)&qcs[t][k4*4];
            float4 h4 = *(const float4*)&khs[u][k4*4];
            s = fmaf(q4.x,h4.x, fmaf(q4.y,h4.y, fmaf(q4.z,h4.z, fmaf(q4.w,h4.w, s))));
        }
        Ss[t][u] = (u <= t) ? s : 0.f;
    }
    __syncthreads();

    if (tid < LL){
        int t = tid;
        float d = EPSV;
        for (int u=0; u<=t; u++) d += Ss[t][u];
        #pragma unroll 8
        for (int kk=0; kk<DD; kk++) d += qcs[t][kk]*z0s[kk];
        denS[t] = d;
    }
    __syncthreads();

    const int t  = tid >> 4;
    const int jg = tid & 15;
    const int j0 = jg * 8;
    float y8[8];
    #pragma unroll
    for (int jj=0;jj<8;jj++) y8[jj]=0.f;

    // intra-chunk: sum_u S[t][u] * v[u][j]
    #pragma unroll
    for (int u=0; u<LL; u++){
        float sv = Ss[t][u];
        float4 v4a = *(const float4*)&vsm[u][j0];
        float4 v4b = *(const float4*)&vsm[u][j0+4];
        y8[0]=fmaf(sv,v4a.x,y8[0]); y8[1]=fmaf(sv,v4a.y,y8[1]);
        y8[2]=fmaf(sv,v4a.z,y8[2]); y8[3]=fmaf(sv,v4a.w,y8[3]);
        y8[4]=fmaf(sv,v4b.x,y8[4]); y8[5]=fmaf(sv,v4b.y,y8[5]);
        y8[6]=fmaf(sv,v4b.z,y8[6]); y8[7]=fmaf(sv,v4b.w,y8[7]);
    }

    // inter-chunk: sum_i qc[t][i] * s0[i][j], staged in 8 slices of 16 rows
    const float* s0g = ws + OFF_S0 + (size_t)bc*DD*DD;
    for (int isl=0; isl<8; isl++){
        __syncthreads();
        {
            const float4* src = (const float4*)(s0g + (size_t)isl*16*DD);
            int f = tid;
            *(float4*)&s0s[f>>5][(f&31)*4] = src[f];
            f = tid + 256;
            *(float4*)&s0s[f>>5][(f&31)*4] = src[f];
        }
        __syncthreads();
        #pragma unroll
        for (int ii=0; ii<16; ii++){
            float qv = qcs[t][isl*16+ii];
            float4 s4a = *(const float4*)&s0s[ii][j0];
            float4 s4b = *(const float4*)&s0s[ii][j0+4];
            y8[0]=fmaf(qv,s4a.x,y8[0]); y8[1]=fmaf(qv,s4a.y,y8[1]);
            y8[2]=fmaf(qv,s4a.z,y8[2]); y8[3]=fmaf(qv,s4a.w,y8[3]);
            y8[4]=fmaf(qv,s4b.x,y8[4]); y8[5]=fmaf(qv,s4b.y,y8[5]);
            y8[6]=fmaf(qv,s4b.z,y8[6]); y8[7]=fmaf(qv,s4b.w,y8[7]);
        }
    }

    const float rd = 1.f/denS[t];
    float* yg = y + (size_t)(b*TT + t0 + t)*DD + j0;
    float4 o0 = make_float4(y8[0]*rd, y8[1]*rd, y8[2]*rd, y8[3]*rd);
    float4 o1 = make_float4(y8[4]*rd, y8[5]*rd, y8[6]*rd, y8[7]*rd);
    *(float4*)(yg)     = o0;
    *(float4*)(yg + 4) = o1;
}

extern "C" void kernel_launch(void* const* d_in, const int* in_sizes, int n_in,
                              void* d_out, int out_size, void* d_ws, size_t ws_size,
                              hipStream_t stream)
{
    const float* x  = (const float*)d_in[0];
    const float* Wq = (const float*)d_in[1]; const float* bq = (const float*)d_in[2];
    const float* Wk = (const float*)d_in[3]; const float* bk = (const float*)d_in[4];
    const float* Wv = (const float*)d_in[5]; const float* bv = (const float*)d_in[6];
    const float* Wa = (const float*)d_in[7]; const float* ba = (const float*)d_in[8];
    float* ws = (float*)d_ws;
    float* yo = (float*)d_out;

    hipLaunchKernelGGL(k_proj, dim3(BB*CC), dim3(256), 0, stream,
                       x, Wq,bq, Wk,bk, Wv,bv, Wa,ba, ws);
    hipLaunchKernelGGL(k_scan, dim3(BB*DD), dim3(128), 0, stream, ws);
    hipLaunchKernelGGL(k_out,  dim3(BB*CC), dim3(256), 0, stream, ws, yo);
}